// Round 8
// baseline (395.945 us; speedup 1.0000x reference)
//
#include <hip/hip_runtime.h>
#include <hip/hip_bf16.h>

// LaCT Audio Block — bf16 MFMA v7.
// All LDS staging via global_load_lds (width 16) with pre-swizzled global
// source addresses + double-buffered LDS (T3 2-phase). Attention: no reg
// prefetch, half-split S processing to fit arch VGPRs (kill AGPR churn).

typedef __bf16 bf16_t;
typedef __bf16 bf16x8 __attribute__((ext_vector_type(8)));
typedef __bf16 bf16x4 __attribute__((ext_vector_type(4)));
typedef float  f32x4  __attribute__((ext_vector_type(4)));
typedef float  f32x16 __attribute__((ext_vector_type(16)));

#define SW64(r,cg) ((cg) ^ ((r)&7))        // 64-elem (128B) rows, granule 0..7
#define SW32(r,cg) ((cg) ^ (((r)>>2)&3))   // 32-elem (64B) rows, granule 0..3

static __device__ __forceinline__ f32x4 mfma16(bf16x8 a, bf16x8 b, f32x4 c){
  return __builtin_amdgcn_mfma_f32_16x16x32_bf16(a, b, c, 0, 0, 0);
}
static __device__ __forceinline__ f32x16 mfma32(bf16x8 a, bf16x8 b, f32x16 c){
  return __builtin_amdgcn_mfma_f32_32x32x16_bf16(a, b, c, 0, 0, 0);
}
__device__ __forceinline__ float sigm(float x){ return 1.0f/(1.0f + __expf(-x)); }
static __device__ __forceinline__ unsigned pkbf(float lo, float hi){
  unsigned short a = __builtin_bit_cast(unsigned short, (__bf16)lo);
  unsigned short b = __builtin_bit_cast(unsigned short, (__bf16)hi);
  return (unsigned)a | ((unsigned)b<<16);
}
static __device__ __forceinline__ float unpk_lo(unsigned u){
  return (float)__builtin_bit_cast(__bf16,(unsigned short)(u&0xffffu));
}
static __device__ __forceinline__ float unpk_hi(unsigned u){
  return (float)__builtin_bit_cast(__bf16,(unsigned short)(u>>16));
}
static __device__ __forceinline__ float hswap_add(float x){
  float a=x, b=x;
  asm volatile("v_permlane32_swap_b32 %0, %1" : "+v"(a), "+v"(b));
  return a+b;
}
// async global->LDS, 16B per lane; LDS dest is linear (wave base + lane*16).
static __device__ __forceinline__ void gload16(const bf16_t* g, bf16_t* l){
  __builtin_amdgcn_global_load_lds(
      (const __attribute__((address_space(1))) void*)g,
      (__attribute__((address_space(3))) void*)l, 16, 0, 0);
}

// ---------------- LayerNorm (bf16 out) ----------------
__global__ __launch_bounds__(256) void ln_kernel(const float* __restrict__ x,
    const float* __restrict__ w, const float* __restrict__ b,
    bf16_t* __restrict__ xnb)
{
  int s = blockIdx.x, t = threadIdx.x;
  const float4* xr = (const float4*)(x + (size_t)s*1024);
  float4 v = xr[t];
  float sum = v.x+v.y+v.z+v.w;
  float ss  = v.x*v.x+v.y*v.y+v.z*v.z+v.w*v.w;
  #pragma unroll
  for (int o=32;o>0;o>>=1){ sum += __shfl_down(sum,o); ss += __shfl_down(ss,o); }
  __shared__ float red[8];
  __shared__ float stats[2];
  int wid=t>>6, lane=t&63;
  if(lane==0){ red[wid]=sum; red[4+wid]=ss; }
  __syncthreads();
  if(t==0){
    float S0=red[0]+red[1]+red[2]+red[3];
    float Q0=red[4]+red[5]+red[6]+red[7];
    float mu=S0*(1.0f/1024.0f);
    float var=Q0*(1.0f/1024.0f)-mu*mu;
    stats[0]=mu; stats[1]=rsqrtf(var+1e-5f);
  }
  __syncthreads();
  float mu=stats[0], rs=stats[1];
  float4 wv=((const float4*)w)[t], bv=((const float4*)b)[t];
  float4 o;
  o.x=(v.x-mu)*rs*wv.x+bv.x;
  o.y=(v.y-mu)*rs*wv.y+bv.y;
  o.z=(v.z-mu)*rs*wv.z+bv.z;
  o.w=(v.w-mu)*rs*wv.w+bv.w;
  bf16x4 ob = { (bf16_t)o.x, (bf16_t)o.y, (bf16_t)o.z, (bf16_t)o.w };
  *(bf16x4*)&xnb[(size_t)s*1024 + t*4] = ob;
}

// ---------------- weight convert (+ w1 transpose) ----------------
__global__ __launch_bounds__(256) void prep_weights(
  const float* __restrict__ ipw, const float* __restrict__ opw,
  const float* __restrict__ w0, const float* __restrict__ w2,
  const float* __restrict__ w1,
  bf16_t* __restrict__ ipwb, bf16_t* __restrict__ opwb,
  bf16_t* __restrict__ w0b, bf16_t* __restrict__ w2b, bf16_t* __restrict__ w1tb)
{
  long i = ((long)blockIdx.x*256 + threadIdx.x)*4;
  if (i < 3145728) {
    float4 v = *(const float4*)(ipw + i);
    bf16x4 o = {(bf16_t)v.x,(bf16_t)v.y,(bf16_t)v.z,(bf16_t)v.w};
    *(bf16x4*)&ipwb[i] = o;
  } else if (i < 4194304) {
    long j = i - 3145728;
    float4 v = *(const float4*)(opw + j);
    bf16x4 o = {(bf16_t)v.x,(bf16_t)v.y,(bf16_t)v.z,(bf16_t)v.w};
    *(bf16x4*)&opwb[j] = o;
  } else if (i < 4456448) {
    long j = i - 4194304;
    float4 v = *(const float4*)(w0 + j);
    bf16x4 o = {(bf16_t)v.x,(bf16_t)v.y,(bf16_t)v.z,(bf16_t)v.w};
    *(bf16x4*)&w0b[j] = o;
  } else if (i < 4718592) {
    long j = i - 4456448;
    float4 v = *(const float4*)(w2 + j);
    bf16x4 o = {(bf16_t)v.x,(bf16_t)v.y,(bf16_t)v.z,(bf16_t)v.w};
    *(bf16x4*)&w2b[j] = o;
  } else if (i < 4980736) {
    long j = i - 4718592;                    // w1 [4][256][256] -> w1t
    int h = (int)(j>>16), rem = (int)(j&65535), d = rem>>8, e0 = rem&255;
    float4 v = *(const float4*)(w1 + j);
    bf16_t* dst = w1tb + h*65536 + d;
    dst[(e0+0)*256] = (bf16_t)v.x;
    dst[(e0+1)*256] = (bf16_t)v.y;
    dst[(e0+2)*256] = (bf16_t)v.z;
    dst[(e0+3)*256] = (bf16_t)v.w;
  }
}

// ---------------- xn transpose: xnb[4096][1024] -> xnT[16][256][1024] ----------------
__global__ __launch_bounds__(256) void xnT_kernel(const bf16_t* __restrict__ xnb,
                                                  bf16_t* __restrict__ xt)
{
  int dt = blockIdx.x, ct = blockIdx.y, bz = blockIdx.z;
  int nb = bz>>2, hb = bz&3;
  int t = threadIdx.x;
  __shared__ __align__(16) bf16_t T[4096];
  int r = t>>2, seg = t&3;
  const bf16_t* src = xnb + ((size_t)nb*1024 + ct*64 + r)*1024 + hb*256 + dt*64 + seg*16;
  uint4 a0 = *(const uint4*)src;
  uint4 a1 = *(const uint4*)(src + 8);
  *(uint4*)&T[r*64 + ((((seg*2  )&7)^(r&7))<<3)] = a0;
  *(uint4*)&T[r*64 + ((((seg*2+1)&7)^(r&7))<<3)] = a1;
  __syncthreads();
  int d = t>>2, s2 = t&3;
  unsigned uu[8];
  #pragma unroll
  for (int p=0;p<8;p++){
    int c0 = s2*16 + 2*p, c1 = c0+1;
    unsigned short e0 = __builtin_bit_cast(unsigned short,
        T[c0*64 + (((d>>3)^(c0&7))<<3) + (d&7)]);
    unsigned short e1 = __builtin_bit_cast(unsigned short,
        T[c1*64 + (((d>>3)^(c1&7))<<3) + (d&7)]);
    uu[p] = (unsigned)e0 | ((unsigned)e1<<16);
  }
  uint4 o0 = {uu[0],uu[1],uu[2],uu[3]}, o1 = {uu[4],uu[5],uu[6],uu[7]};
  bf16_t* dst = xt + (size_t)bz*262144 + (size_t)(dt*64 + d)*1024 + ct*64 + s2*16;
  *(uint4*)dst = o0;
  *(uint4*)(dst+8) = o1;
}

// ---------------- 128x128 GEMM core: acc += A[m0..,:K] * B[n0..,:K]^T ----------
// Double-buffered LDS, global_load_lds staging with pre-swizzled source.
__device__ __forceinline__ void gemm_core(
    const bf16_t* __restrict__ A, int lda,
    const bf16_t* __restrict__ B, int ldb,
    int K, int m0, int n0, f32x4 (&acc)[4][4])
{
  int t = threadIdx.x, l = t&63;
  int w = t>>6, wr = w>>1, wc = w&1;
  __shared__ __align__(16) bf16_t As[2][4096], Bs[2][4096];
  int row0 = t>>2, gs0 = t&3;
  int swz = (gs0 ^ ((row0>>2)&3))<<3;
  const bf16_t* Aa = A + (size_t)(m0+row0)*lda + swz;
  const bf16_t* Ba = B + (size_t)(n0+row0)*ldb + swz;
  size_t lda64 = (size_t)64*lda, ldb64 = (size_t)64*ldb;

  gload16(Aa,         &As[0][t*8]);
  gload16(Aa + lda64, &As[0][(t+256)*8]);
  gload16(Ba,         &Bs[0][t*8]);
  gload16(Ba + ldb64, &Bs[0][(t+256)*8]);
  __syncthreads();
  int cur = 0;
  for (int k0=0; k0<K; k0+=32) {
    if (k0+32 < K) {
      int nb2 = cur^1;
      gload16(Aa + k0+32,         &As[nb2][t*8]);
      gload16(Aa + lda64 + k0+32, &As[nb2][(t+256)*8]);
      gload16(Ba + k0+32,         &Bs[nb2][t*8]);
      gload16(Ba + ldb64 + k0+32, &Bs[nb2][(t+256)*8]);
    }
    bf16x8 af[4], bb[4];
    #pragma unroll
    for (int mt=0;mt<4;mt++){
      int row = (wr<<6)+(mt<<4)+(l&15);
      af[mt] = *(bf16x8*)&As[cur][row*32 + (SW32(row, (l>>4))<<3)];
    }
    #pragma unroll
    for (int nt=0;nt<4;nt++){
      int row = (wc<<6)+(nt<<4)+(l&15);
      bb[nt] = *(bf16x8*)&Bs[cur][row*32 + (SW32(row, (l>>4))<<3)];
    }
    #pragma unroll
    for (int mt=0;mt<4;mt++)
      #pragma unroll
      for (int nt=0;nt<4;nt++)
        acc[mt][nt] = mfma16(af[mt], bb[nt], acc[mt][nt]);
    __syncthreads();
    cur ^= 1;
  }
}

// ---------------- 128x64 GEMM core (narrow tiles) ----------------
__device__ __forceinline__ void gemm_core_w(
    const bf16_t* __restrict__ A, int lda,
    const bf16_t* __restrict__ B, int ldb,
    int K, int m0, int n0, f32x4 (&acc)[4][2])
{
  int t = threadIdx.x, l = t&63;
  int w = t>>6, wr = w>>1, wc = w&1;
  __shared__ __align__(16) bf16_t As[2][4096], Bs[2][2048];
  int row0 = t>>2, gs0 = t&3;
  int swz = (gs0 ^ ((row0>>2)&3))<<3;
  const bf16_t* Aa = A + (size_t)(m0+row0)*lda + swz;
  const bf16_t* Ba = B + (size_t)(n0+row0)*ldb + swz;
  size_t lda64 = (size_t)64*lda;

  gload16(Aa,         &As[0][t*8]);
  gload16(Aa + lda64, &As[0][(t+256)*8]);
  gload16(Ba,         &Bs[0][t*8]);
  __syncthreads();
  int cur = 0;
  for (int k0=0; k0<K; k0+=32) {
    if (k0+32 < K) {
      int nb2 = cur^1;
      gload16(Aa + k0+32,         &As[nb2][t*8]);
      gload16(Aa + lda64 + k0+32, &As[nb2][(t+256)*8]);
      gload16(Ba + k0+32,         &Bs[nb2][t*8]);
    }
    bf16x8 af[4], bb[2];
    #pragma unroll
    for (int mt=0;mt<4;mt++){
      int row = (wr<<6)+(mt<<4)+(l&15);
      af[mt] = *(bf16x8*)&As[cur][row*32 + (SW32(row, (l>>4))<<3)];
    }
    #pragma unroll
    for (int nt=0;nt<2;nt++){
      int row = (wc<<5)+(nt<<4)+(l&15);
      bb[nt] = *(bf16x8*)&Bs[cur][row*32 + (SW32(row, (l>>4))<<3)];
    }
    #pragma unroll
    for (int mt=0;mt<4;mt++)
      #pragma unroll
      for (int nt=0;nt<2;nt++)
        acc[mt][nt] = mfma16(af[mt], bb[nt], acc[mt][nt]);
    __syncthreads();
    cur ^= 1;
  }
}

#define EPILOOP(...) { int l=threadIdx.x&63, w_=threadIdx.x>>6, wr=w_>>1, wc=w_&1; \
  _Pragma("unroll") for(int mt=0;mt<4;mt++) _Pragma("unroll") for(int nt=0;nt<4;nt++) \
  _Pragma("unroll") for(int q=0;q<4;q++){ \
    int gr=m0+(wr<<6)+(mt<<4)+((l>>4)<<2)+q; int gc=n0+(wc<<6)+(nt<<4)+(l&15); \
    float v=acc[mt][nt][q]; __VA_ARGS__ } }

#define ACCZERO(acc) \
  _Pragma("unroll") for(int i_=0;i_<4;i_++) _Pragma("unroll") for(int j_=0;j_<4;j_++){ \
    f32x4 z_={0.f,0.f,0.f,0.f}; acc[i_][j_]=z_; }

#define ACCZERO_W(acc) \
  _Pragma("unroll") for(int i_=0;i_<4;i_++) _Pragma("unroll") for(int j_=0;j_<2;j_++){ \
    f32x4 z_={0.f,0.f,0.f,0.f}; acc[i_][j_]=z_; }

// ---------------- big GEMMs (qkv / out_proj), M=4096 ----------------
template<int EPI>
__global__ __launch_bounds__(256) void gemm_big(
  const bf16_t* __restrict__ A, const bf16_t* __restrict__ B,
  float* __restrict__ C, const float* __restrict__ bias,
  bf16_t* __restrict__ O1, bf16_t* __restrict__ O2, bf16_t* __restrict__ O3,
  int K, int ldc)
{
  int m0 = blockIdx.y<<7, n0 = blockIdx.x<<7;
  f32x4 acc[4][4];
  ACCZERO(acc)
  gemm_core(A, K, B, K, K, m0, n0, acc);
  EPILOOP(
    if constexpr (EPI==1) {
      C[(size_t)gr*ldc + gc] = v + bias[gc];
    } else {
      v += bias[gc];
      int seg = gc>>10; int c2 = gc&1023; int hh = c2>>6; int dd = c2&63;
      size_t oi = ((size_t)hh*4096 + gr)*64 + dd;
      if (seg==0)      O1[oi] = (bf16_t)(v*0.18033688011112042f); // 0.125*log2(e)
      else if (seg==1) O2[oi] = (bf16_t)v;
      else             O3[oi] = (bf16_t)v;
    }
  )
}

// ---------------- LaCT fwd + ew1 + transpose, fused ----------------
__global__ __launch_bounds__(256) void lact_fwd_ew(
    const bf16_t* __restrict__ xnb,
    const bf16_t* __restrict__ w0b, const bf16_t* __restrict__ w2b,
    const bf16_t* __restrict__ w1tb,
    bf16_t* __restrict__ hT, bf16_t* __restrict__ pT, bf16_t* __restrict__ gT)
{
  int bz = blockIdx.z, hb = bz&3;
  const bf16_t* A = xnb + (size_t)(bz>>2)*1048576 + (size_t)hb*256;
  int m0 = blockIdx.y<<7, n0 = blockIdx.x<<6;
  f32x4 acc[4][2];
  unsigned gpk[4][2][2], ppk[4][2][2];

  ACCZERO_W(acc)
  gemm_core_w(A, 1024, w0b + hb*65536, 256, 256, m0, n0, acc);     // gate
  #pragma unroll
  for (int mt=0;mt<4;mt++)
    #pragma unroll
    for (int nt=0;nt<2;nt++){
      gpk[mt][nt][0] = pkbf(acc[mt][nt][0], acc[mt][nt][1]);
      gpk[mt][nt][1] = pkbf(acc[mt][nt][2], acc[mt][nt][3]);
    }
  ACCZERO_W(acc)
  gemm_core_w(A, 1024, w2b + hb*65536, 256, 256, m0, n0, acc);     // g
  #pragma unroll
  for (int mt=0;mt<4;mt++)
    #pragma unroll
    for (int nt=0;nt<2;nt++){
      ppk[mt][nt][0] = pkbf(acc[mt][nt][0], acc[mt][nt][1]);
      ppk[mt][nt][1] = pkbf(acc[mt][nt][2], acc[mt][nt][3]);
    }
  ACCZERO_W(acc)
  gemm_core_w(A, 1024, w1tb + hb*65536, 256, 256, m0, n0, acc);    // +C@w1

  int l=threadIdx.x&63, w_=threadIdx.x>>6, wr=w_>>1, wc=w_&1;
  size_t tb = (size_t)bz*262144;
  #pragma unroll
  for (int mt=0;mt<4;mt++){
    #pragma unroll
    for (int nt=0;nt<2;nt++){
      int gc = n0 + (wc<<5) + (nt<<4) + (l&15);
      size_t rowoff = tb + (size_t)gc*1024;
      #pragma unroll
      for (int qp=0;qp<2;qp++){
        int gr0 = m0 + (wr<<6) + (mt<<4) + ((l>>4)<<2) + 2*qp;
        float gate0 = unpk_lo(gpk[mt][nt][qp]), gate1 = unpk_hi(gpk[mt][nt][qp]);
        float g0 = unpk_lo(ppk[mt][nt][qp]), g1 = unpk_hi(ppk[mt][nt][qp]);
        float dh0 = acc[mt][nt][2*qp], dh1 = acc[mt][nt][2*qp+1];
        float sg0 = sigm(gate0), sg1 = sigm(gate1);
        float hs0 = gate0*sg0, hs1 = gate1*sg1;
        float hid0 = hs0*g0, hid1 = hs1*g1;
        float nd0 = -dh0, nd1 = -dh1;
        float dpre0 = nd0*g0*(sg0 + gate0*sg0*(1.0f-sg0));
        float dpre1 = nd1*g1*(sg1 + gate1*sg1*(1.0f-sg1));
        float dg0 = nd0*hs0, dg1 = nd1*hs1;
        *(unsigned*)&hT[rowoff + gr0] = pkbf(hid0, hid1);
        *(unsigned*)&pT[rowoff + gr0] = pkbf(dpre0, dpre1);
        *(unsigned*)&gT[rowoff + gr0] = pkbf(dg0, dg1);
      }
    }
  }
}

// ---------------- LaCT apply + ew2, fused -> u bf16 ----------------
__global__ __launch_bounds__(256) void lact_apply_u(
    const bf16_t* __restrict__ xnb,
    const bf16_t* __restrict__ w0nb, const bf16_t* __restrict__ w2nb,
    bf16_t* __restrict__ u)
{
  int bz = blockIdx.z;
  const bf16_t* A = xnb + (size_t)(bz>>2)*1048576 + (size_t)(bz&3)*256;
  int m0 = blockIdx.y<<7, n0 = blockIdx.x<<6;
  f32x4 acc[4][2];
  unsigned qpk[4][2][2];

  ACCZERO_W(acc)
  gemm_core_w(A, 1024, w2nb + (size_t)bz*65536, 256, 256, m0, n0, acc);  // gq2
  #pragma unroll
  for (int mt=0;mt<4;mt++)
    #pragma unroll
    for (int nt=0;nt<2;nt++){
      qpk[mt][nt][0] = pkbf(acc[mt][nt][0], acc[mt][nt][1]);
      qpk[mt][nt][1] = pkbf(acc[mt][nt][2], acc[mt][nt][3]);
    }
  ACCZERO_W(acc)
  gemm_core_w(A, 1024, w0nb + (size_t)bz*65536, 256, 256, m0, n0, acc);  // gq

  int l=threadIdx.x&63, w_=threadIdx.x>>6, wr=w_>>1, wc=w_&1;
  size_t tb = (size_t)bz*262144;
  #pragma unroll
  for (int mt=0;mt<4;mt++){
    #pragma unroll
    for (int nt=0;nt<2;nt++){
      int gc = n0 + (wc<<5) + (nt<<4) + (l&15);
      #pragma unroll
      for (int qp=0;qp<2;qp++){
        int gr0 = m0 + (wr<<6) + (mt<<4) + ((l>>4)<<2) + 2*qp;
        float q20 = unpk_lo(qpk[mt][nt][qp]), q21 = unpk_hi(qpk[mt][nt][qp]);
        float gq0 = acc[mt][nt][2*qp], gq1 = acc[mt][nt][2*qp+1];
        u[tb + (size_t)gr0*256 + gc]     = (bf16_t)(gq0*sigm(gq0)*q20);
        u[tb + (size_t)(gr0+1)*256 + gc] = (bf16_t)(gq1*sigm(gq1)*q21);
      }
    }
  }
}

// ---------------- LaCT weight updates: 3 GEMMs, 128x64 tiles ----------------
__global__ __launch_bounds__(256) void lact_upd(
    const bf16_t* __restrict__ xnTb, const bf16_t* __restrict__ hTb,
    const bf16_t* __restrict__ pTb,  const bf16_t* __restrict__ gTb,
    const float* __restrict__ w1, const float* __restrict__ w0,
    const float* __restrict__ w2,
    bf16_t* __restrict__ w1nb, bf16_t* __restrict__ w0nb, bf16_t* __restrict__ w2nb)
{
  int zz = blockIdx.z, sub = zz>>4, bz = zz&15, hb = bz&3;
  const bf16_t* A = (sub==0? xnTb : (sub==1? pTb : gTb)) + (size_t)bz*262144;
  const bf16_t* B = (sub==0? hTb : xnTb) + (size_t)bz*262144;
  const float*  P = (sub==0? w1 : (sub==1? w0 : w2)) + (size_t)hb*65536;
  bf16_t*       O = (sub==0? w1nb : (sub==1? w0nb : w2nb)) + (size_t)bz*65536;
  float sgn = (sub==0) ? 1.0f : -1.0f;
  int m0 = blockIdx.y<<7, n0 = blockIdx.x<<6;
  f32x4 acc[4][2];
  ACCZERO_W(acc)
  gemm_core_w(A, 1024, B, 1024, 1024, m0, n0, acc);
  int l=threadIdx.x&63, w_=threadIdx.x>>6, wr=w_>>1, wc=w_&1;
  #pragma unroll
  for (int mt=0;mt<4;mt++){
    #pragma unroll
    for (int nt=0;nt<2;nt++){
      int gc = n0 + (wc<<5) + (nt<<4) + (l&15);
      #pragma unroll
      for (int q=0;q<4;q++){
        int gr = m0 + (wr<<6) + (mt<<4) + ((l>>4)<<2) + q;
        O[(size_t)gr*256 + gc] =
            (bf16_t)(P[(size_t)gr*256 + gc] + sgn*acc[mt][nt][q]);
      }
    }
  }
}

// ---------------- LaCT final: d_out += u @ w1n^T ----------------
__global__ __launch_bounds__(256) void lact_final(
    const bf16_t* __restrict__ u, const bf16_t* __restrict__ w1nb,
    float* __restrict__ out)
{
  int bz = blockIdx.z;
  const bf16_t* A = u + (size_t)bz*262144;
  const bf16_t* B = w1nb + (size_t)bz*65536;
  float* C = out + (size_t)(bz>>2)*1048576 + (size_t)(bz&3)*256;
  int m0 = blockIdx.y<<7, n0 = (blockIdx.x&1)<<7;
  f32x4 acc[4][4];
  ACCZERO(acc)
  gemm_core(A, 256, B, 256, 256, m0, n0, acc);
  EPILOOP( C[(size_t)gr*1024 + gc] += v; )
}

// ---------------- V transpose: Vb[h][s][d] -> Vt[h][d][s] ----------------
__global__ __launch_bounds__(256) void vtrans(const bf16_t* __restrict__ Vb,
                                              bf16_t* __restrict__ Vt)
{
  int st = blockIdx.x, h = blockIdx.y, t = threadIdx.x;
  __shared__ __align__(16) bf16_t T[64*72];
  #pragma unroll
  for (int G=t; G<512; G+=256) {
    int r = G>>3, cg = G&7;
    *(uint4*)&T[r*72 + cg*8] =
      *(const uint4*)(Vb + ((size_t)h*4096 + st*64 + r)*64 + cg*8);
  }
  __syncthreads();
  int d = t>>2, seg = t&3;
  bf16x8 e0, e1;
  #pragma unroll
  for (int i=0;i<8;i++)  e0[i] = T[(seg*16+i)*72 + d];
  #pragma unroll
  for (int i=0;i<8;i++)  e1[i] = T[(seg*16+8+i)*72 + d];
  size_t base = ((size_t)h*64 + d)*4096 + st*64 + seg*16;
  *(bf16x8*)(Vt + base)     = e0;
  *(bf16x8*)(Vt + base + 8) = e1;
}

// ---------------- MFMA flash attention, split-K=2, gload_lds staging ----------
// grid (16 heads, 32 qblocks, 2 kv-halves); 4 waves; wave w: 32 q rows.
__global__ __launch_bounds__(256) void attn_mfma4(
    const bf16_t* __restrict__ Qb, const bf16_t* __restrict__ Kb,
    const bf16_t* __restrict__ Vt, float* __restrict__ Opart,
    float* __restrict__ lpart)
{
  int h = blockIdx.x, qblk = blockIdx.y, z = blockIdx.z;
  int t = threadIdx.x, w = t>>6, l = t&63;
  int lh = l>>5, lq = l&31;
  __shared__ __align__(16) bf16_t Ks[2][4096], Vs[2][4096];

  const bf16_t* Kg = Kb + (size_t)h*262144 + (size_t)z*131072;   // 2048 key rows
  const bf16_t* Vg = Vt + (size_t)h*262144 + (size_t)z*2048;     // 2048 key cols

  bf16x8 qf[4];
  {
    const bf16_t* Qg = Qb + ((size_t)h*4096 + (size_t)qblk*128 + w*32 + lq)*64 + lh*8;
    #pragma unroll
    for (int s=0;s<4;s++) qf[s] = *(const bf16x8*)(Qg + s*16);
  }

  // staging: slot s -> row=s>>3, granule gs=s&7; global granule = gs^(row&7).
  int srow = t>>3, sgs = t&7;
  const bf16_t* ka = Kg + (size_t)srow*64   + ((sgs^(srow&7))<<3);
  const bf16_t* va = Vg + (size_t)srow*4096 + ((sgs^(srow&7))<<3);

  float l_r = 0.f;
  f32x16 Oa, Ob;
  #pragma unroll
  for (int i=0;i<16;i++){ Oa[i]=0.f; Ob[i]=0.f; }

  #define STAGE_ATTN(buf, kt) { \
    gload16(ka + (size_t)(kt)*4096,          &Ks[buf][t*8]); \
    gload16(ka + (size_t)(kt)*4096 + 2048,   &Ks[buf][(t+256)*8]); \
    gload16(va + (size_t)(kt)*64,            &Vs[buf][t*8]); \
    gload16(va + (size_t)(kt)*64 + 131072,   &Vs[buf][(t+256)*8]); }

  STAGE_ATTN(0, 0)
  __syncthreads();
  int cur = 0;

  for (int kt=0; kt<32; ++kt) {
    if (kt < 31) STAGE_ATTN(cur^1, kt+1)
    // QK^T + softmax, half (32 keys) at a time to cap register pressure
    unsigned pk[2][4][2];
    #pragma unroll
    for (int half=0; half<2; ++half){
      f32x16 S;
      #pragma unroll
      for (int i=0;i<16;i++) S[i]=0.f;
      int krow = (half<<5) + lq;
      __builtin_amdgcn_s_setprio(1);
      #pragma unroll
      for (int s=0;s<4;s++){
        int g = (s<<1) + lh;
        bf16x8 kf = *(const bf16x8*)&Ks[cur][krow*64 + (SW64(lq,g)<<3)];
        S = mfma32(kf, qf[s], S);
      }
      __builtin_amdgcn_s_setprio(0);
      #pragma unroll
      for (int i=0;i<16;i++) S[i] = exp2f(S[i]);
      float rt[8];
      #pragma unroll
      for (int i=0;i<8;i++) rt[i] = S[i]+S[i+8];
      #pragma unroll
      for (int i=0;i<4;i++) rt[i] += rt[i+4];
      l_r += (rt[0]+rt[1])+(rt[2]+rt[3]);
      #pragma unroll
      for (int u2=0; u2<4; u2++){
        #pragma unroll
        for (int wd=0; wd<2; wd++){
          int q0 = 4*u2 + 2*wd;
          pk[half][u2][wd] = pkbf(S[q0], S[q0+1]);
        }
      }
    }
    // PV: A = P rows=query (via permlane32_swap), B = V^T rows=d
    __builtin_amdgcn_s_setprio(1);
    #pragma unroll
    for (int ks=0; ks<4; ks++){
      int hsel = ks>>1, v0 = 2*(ks&1);
      unsigned x0 = pk[hsel][v0][0],   x1 = pk[hsel][v0][1];
      unsigned y0 = pk[hsel][v0+1][0], y1 = pk[hsel][v0+1][1];
      asm volatile("v_permlane32_swap_b32 %0, %1" : "+v"(x0), "+v"(y0));
      asm volatile("v_permlane32_swap_b32 %0, %1" : "+v"(x1), "+v"(y1));
      uint4 pau = {x0, x1, y0, y1};
      bf16x8 pa = __builtin_bit_cast(bf16x8, pau);
      int g = (ks<<1) + lh;
      bf16x8 vf0 = *(const bf16x8*)&Vs[cur][lq*64 + (SW64(lq,g)<<3)];
      int rowb = 32 + lq;
      bf16x8 vf1 = *(const bf16x8*)&Vs[cur][rowb*64 + (SW64(lq,g)<<3)];
      Oa = mfma32(pa, vf0, Oa);
      Ob = mfma32(pa, vf1, Ob);
    }
    __builtin_amdgcn_s_setprio(0);
    __syncthreads();
    cur ^= 1;
  }
  #undef STAGE_ATTN
  // fold the two key-halves of l (each lane held half the keys for query lq)
  l_r = hswap_add(l_r);
  // store unnormalized partials + l
  size_t pb = ((size_t)(h*32+qblk))*2 + z;
  float* Op = Opart + pb*8192 + (size_t)(w*32)*64;
  #pragma unroll
  for (int reg=0; reg<16; reg++){
    int row = (reg&3) + 8*(reg>>2) + 4*lh;
    Op[row*64 + lq]      = Oa[reg];
    Op[row*64 + 32 + lq] = Ob[reg];
  }
  if (l < 32) {
    lpart[pb*128 + (size_t)(w*32+l)] = l_r;
  }
}

// ---------------- attention merge: O = (O0+O1)/(l0+l1) ----------------
__global__ __launch_bounds__(256) void attn_merge(
    const float* __restrict__ Opart, const float* __restrict__ lpart,
    bf16_t* __restrict__ ao)
{
  int h = blockIdx.x, qblk = blockIdx.y, t = threadIdx.x;
  int r = t>>1, ch = (t&1)<<5;
  size_t b = ((size_t)(h*32+qblk))*2;
  const float* O0 = Opart + b*8192;
  const float* O1 = O0 + 8192;
  float inv = 1.0f/(lpart[b*128 + r] + lpart[b*128 + 128 + r]);
  bf16_t* dst = ao + (size_t)(qblk*128+r)*1024 + h*64 + ch;
  const float* p0 = O0 + r*64 + ch;
  const float* p1 = O1 + r*64 + ch;
  #pragma unroll
  for (int j=0;j<8;j++){
    float4 o0 = *(const float4*)(p0 + j*4);
    float4 o1 = *(const float4*)(p1 + j*4);
    bf16x4 ov;
    ov[0]=(bf16_t)((o0.x+o1.x)*inv);
    ov[1]=(bf16_t)((o0.y+o1.y)*inv);
    ov[2]=(bf16_t)((o0.z+o1.z)*inv);
    ov[3]=(bf16_t)((o0.w+o1.w)*inv);
    *(bf16x4*)(dst + j*4) = ov;
  }
}

extern "C" void kernel_launch(void* const* d_in, const int* in_sizes, int n_in,
                              void* d_out, int out_size, void* d_ws, size_t ws_size,
                              hipStream_t stream) {
  const float* x          = (const float*)d_in[0];
  const float* ln_w       = (const float*)d_in[1];
  const float* ln_b       = (const float*)d_in[2];
  const float* in_proj_w  = (const float*)d_in[3];
  const float* in_proj_b  = (const float*)d_in[4];
  const float* out_proj_w = (const float*)d_in[5];
  const float* out_proj_b = (const float*)d_in[6];
  const float* w0         = (const float*)d_in[7];
  const float* w1         = (const float*)d_in[8];
  const float* w2         = (const float*)d_in[9];
  float* out = (float*)d_out;

  float* ws = (float*)d_ws;
  bf16_t* xnb  = (bf16_t*)(ws);              // 4,194,304 bf16
  bf16_t* Qb   = (bf16_t*)(ws + 2097152);
  bf16_t* Kb   = (bf16_t*)(ws + 4194304);
  bf16_t* Vb   = (bf16_t*)(ws + 6291456);    // overlay: later u bf16
  bf16_t* ub   = (bf16_t*)(ws + 6291456);
  bf16_t* aob  = (bf16_t*)(ws + 10485760);
  bf16_t* Vtp  = (bf16_t*)(ws + 14680064);
  bf16_t* xnTb = (bf16_t*)(ws + 18874368);
  bf16_t* hTb  = (bf16_t*)(ws + 20971520);
  bf16_t* pTb  = (bf16_t*)(ws + 23068672);
  bf16_t* gTb  = (bf16_t*)(ws + 25165824);
  float*  Opart= ws + 18874368;              // overlay xnTb..gTb (8,388,608 f32)
  bf16_t* ipwb = (bf16_t*)(ws + 27262976);
  float*  lp   = ws + 27262976;              // overlay ipwb (131,072 f32, post-qkv)
  bf16_t* opwb = (bf16_t*)(ws + 28835840);
  bf16_t* w0b  = (bf16_t*)(ws + 29360128);
  bf16_t* w2b  = (bf16_t*)(ws + 29491200);
  bf16_t* w1tb = (bf16_t*)(ws + 29622272);
  bf16_t* w0nb = (bf16_t*)(ws + 29753344);
  bf16_t* w1nb = (bf16_t*)(ws + 30277632);
  bf16_t* w2nb = (bf16_t*)(ws + 30801920);

  dim3 blk(256);

  // 1) LayerNorm -> bf16
  ln_kernel<<<dim3(4096),blk,0,stream>>>(x, ln_w, ln_b, xnb);

  // 2) weight conversions
  prep_weights<<<dim3(4864),blk,0,stream>>>(in_proj_w, out_proj_w, w0, w2, w1,
                                            ipwb, opwb, w0b, w2b, w1tb);

  // 3) qkv GEMM -> Qb(*0.125*log2e)/Kb/Vb (fused bias)
  gemm_big<3><<<dim3(24,32),blk,0,stream>>>(
      xnb, ipwb, nullptr, in_proj_b, Qb, Kb, Vb, 1024, 0);

  // 4) V transpose per head
  vtrans<<<dim3(64,16),blk,0,stream>>>(Vb, Vtp);

  // 5) flash attention split-K=2 -> partials (no running max)
  attn_mfma4<<<dim3(16,32,2),blk,0,stream>>>(Qb, Kb, Vtp, Opart, lp);

  // 6) merge -> aob bf16
  attn_merge<<<dim3(16,32),blk,0,stream>>>(Opart, lp, aob);

  // 7) out_proj -> d_out fp32 (+bias)
  gemm_big<1><<<dim3(8,32),blk,0,stream>>>(
      aob, opwb, out, out_proj_b, nullptr,nullptr,nullptr, 1024, 1024);

  // 8) xn transpose for weight-update GEMMs
  xnT_kernel<<<dim3(4,16,16),blk,0,stream>>>(xnb, xnTb);

  // 9) LaCT fwd + ew1 + transpose fused -> hT/pT/gT bf16
  lact_fwd_ew<<<dim3(4,8,16),blk,0,stream>>>(xnb, w0b, w2b, w1tb, hTb, pTb, gTb);

  // 10) weight updates (one launch, 128x64 tiles, 384 blocks)
  lact_upd<<<dim3(4,2,48),blk,0,stream>>>(xnTb, hTb, pTb, gTb,
                                          w1, w0, w2, w1nb, w0nb, w2nb);

  // 11) apply + ew2 fused -> u bf16
  lact_apply_u<<<dim3(4,8,16),blk,0,stream>>>(xnb, w0nb, w2nb, ub);

  // 12) d_out += u @ w1n^T
  lact_final<<<dim3(2,8,16),blk,0,stream>>>(ub, w1nb, out);
}